// Round 11
// baseline (401.827 us; speedup 1.0000x reference)
//
#include <hip/hip_runtime.h>

// SimpleMemoryNetwork: T=64,B=128,H=256,NI=2,NO=10, lambda=.95, eta=.5, sample=32, decision=8
// R11 = R10 with the o-broadcast race FIXED: o64 gains the batch-group dimension,
// o64[33][64][256] (grp-major). R10's bug: all 64 grps raced on o64[33][256].
// Structure (= R6 + c-exchange eliminated):
//  * 256 blocks = 64 batch-groups x 4 col-slices, 512 thr, 1 blk/CU.
//  * o_hist FULL-WIDTH fp32 in LDS (33x2x256); dot coeffs computed block-locally.
//  * o(t-1) broadcast: 64 u64/block published in fin (t<=33); gathered in the SAME
//    phase as the state gather (threads 0..95 o-poll ; 128..511 state-poll).
//    o slots write-once per launch -> no re-sentinel (init re-sentinels each launch).
//  * State/mu sentinel-slot protocol byte-identical to R6 (proven).

typedef unsigned long long u64;

#define HH 256
#define NSTEPS 64

// ws layout (float offsets)
#define OFF_ST 0u           // st64[4][128][256] u64      = 262144 floats
#define OFF_O  262144u      // o64[33][64][256] u64       = 1081344 floats
#define OFF_MU 1343488u     // mu64[4][4][64][32] u64     = 65536 floats
#define WS_FLOATS 1409024u  // ~5.64 MB

#define SENT_STATE   0xBF800000BF800000ull
#define SENT_MU      0x7FC00000u
#define SENT_MU_PAIR 0x7FC000007FC00000ull

#define AGENT __HIP_MEMORY_SCOPE_AGENT
#define RLX   __ATOMIC_RELAXED

__device__ __forceinline__ u64 ld64(const u64* p){ return __hip_atomic_load(p,RLX,AGENT); }
__device__ __forceinline__ void st64s(u64* p,u64 v){ __hip_atomic_store(p,v,RLX,AGENT); }
__device__ __forceinline__ u64 pack2(float lo,float hi){
  return (u64)__float_as_uint(lo) | ((u64)__float_as_uint(hi)<<32);
}

__global__ __launch_bounds__(256) void smn_init(float* __restrict__ ws,
                                                float* __restrict__ out){
  unsigned i = blockIdx.x*256u + threadIdx.x, st = gridDim.x*256u;
  u64* stp=(u64*)(ws+OFF_ST); u64* op=(u64*)(ws+OFF_O); u64* mp=(u64*)(ws+OFF_MU);
  for (unsigned k=i;k<131072u;k+=st) st64s(&stp[k],SENT_STATE);
  for (unsigned k=i;k<540672u;k+=st) st64s(&op[k],SENT_STATE);
  for (unsigned k=i;k<32768u;k+=st)  st64s(&mp[k],SENT_MU_PAIR);
  for (unsigned k=i;k<10240u;k+=st)  out[k]=0.f;
}

__global__ __launch_bounds__(512) void smn_main(
    const float* __restrict__ x_in, const float* __restrict__ W_sr,
    const float* __restrict__ W_ma, const float* __restrict__ W_ro,
    const float* __restrict__ W_ao, const float* __restrict__ W_ar,
    const float* __restrict__ W_ra, const float* __restrict__ W_a,
    const float* __restrict__ W_y,  const float* __restrict__ gvec,
    const float* __restrict__ bvec, float* __restrict__ out,
    float* __restrict__ ws)
{
  __shared__ __align__(16) float aF[2][HH], rF[2][HH];   // full state(t)
  __shared__ __align__(16) float P[2][32][2][64];        // k-split matvec partials (32KB)
  __shared__ __align__(16) float r_hist[33][2][64];      // own-slice r history
  __shared__ __align__(16) float o_hist[33][2][HH];      // FULL-width o history (67.6KB)
  __shared__ float opre[2][64];
  __shared__ float c_l[33][2];
  __shared__ float mu_l[64];
  __shared__ float muG[16][32][2];
  __shared__ float lam_pow[64];
  __shared__ float x_l[2][5];

  const int tid = threadIdx.x;
  const int bid = blockIdx.x;
  const int grp = bid >> 2, jsl = bid & 3;
  const int b0 = grp * 2, c0 = jsl * 64;
  const int q = tid & 15, ks = tid >> 4;       // matvec map: col quad, k-slice of 8

  u64* st64 = (u64*)(ws + OFF_ST);
  u64* o64  = (u64*)(ws + OFF_O);
  u64* mu64 = (u64*)(ws + OFF_MU);

  // per-thread column constants (combine map tid<128 -> b=tid>>6, c=tid&63)
  const int cc2 = c0 + (tid & 63);
  const float gv  = gvec[cc2], bv = bvec[cc2];
  const float wma0=W_ma[cc2], wma1=W_ma[HH+cc2], wma2=W_ma[2*HH+cc2];
  const float wsr0=W_sr[cc2], wsr1=W_sr[HH+cc2];
  if (tid < 64) lam_pow[tid] = powf(0.95f,(float)tid);
  if (tid < 10) x_l[tid/5][tid%5] = x_in[(b0 + tid/5)*5 + tid%5];   // x(0)
  __syncthreads();

  for (int t = 0; t <= NSTEPS; ++t) {
    // ================= A: state(t) own slice =================
    if (t < NSTEPS) {
      if (t == 0) {
        if (tid < 128) {
          int b = tid>>6, c = tid&63;
          float va = fmaxf(x_l[b][2]*wma0 + x_l[b][3]*wma1 + x_l[b][4]*wma2, 0.f);
          float vr = fmaxf(x_l[b][0]*wsr0 + x_l[b][1]*wsr1, 0.f);
          aF[b][c0+c]=va; rF[b][c0+c]=vr; r_hist[0][b][c]=vr;
          st64s(&st64[(unsigned)((b0+b)*HH + cc2)], pack2(va,vr));
        }
        __syncthreads();
      } else {
        const int kb = ks*8;
        float sa0[8],sa1[8],sr0[8],sr1[8];
        *(float4*)&sa0[0]=*(const float4*)&aF[0][kb]; *(float4*)&sa0[4]=*(const float4*)&aF[0][kb+4];
        *(float4*)&sa1[0]=*(const float4*)&aF[1][kb]; *(float4*)&sa1[4]=*(const float4*)&aF[1][kb+4];
        *(float4*)&sr0[0]=*(const float4*)&rF[0][kb]; *(float4*)&sr0[4]=*(const float4*)&rF[0][kb+4];
        *(float4*)&sr1[0]=*(const float4*)&rF[1][kb]; *(float4*)&sr1[4]=*(const float4*)&rF[1][kb+4];
        float aA[2][4]={{0.f,0.f,0.f,0.f},{0.f,0.f,0.f,0.f}};
        float aR[2][4]={{0.f,0.f,0.f,0.f},{0.f,0.f,0.f,0.f}};
        #pragma unroll
        for (int kk=0; kk<8; ++kk) {
          const int k = kb + kk;
          const float4 wa = *(const float4*)&W_a [k*HH + c0 + q*4];
          const float4 wr = *(const float4*)&W_ra[k*HH + c0 + q*4];
          const float4 wn = *(const float4*)&W_ar[k*HH + c0 + q*4];
          #pragma unroll
          for (int jj=0;jj<4;++jj){
            const float waj=(&wa.x)[jj], wrj=(&wr.x)[jj], wnj=(&wn.x)[jj];
            aA[0][jj] += sa0[kk]*waj + sr0[kk]*wrj;
            aA[1][jj] += sa1[kk]*waj + sr1[kk]*wrj;
            aR[0][jj] += sa0[kk]*wnj;
            aR[1][jj] += sa1[kk]*wnj;
          }
        }
        *(float4*)&P[0][ks][0][q*4] = make_float4(aA[0][0],aA[0][1],aA[0][2],aA[0][3]);
        *(float4*)&P[0][ks][1][q*4] = make_float4(aA[1][0],aA[1][1],aA[1][2],aA[1][3]);
        *(float4*)&P[1][ks][0][q*4] = make_float4(aR[0][0],aR[0][1],aR[0][2],aR[0][3]);
        *(float4*)&P[1][ks][1][q*4] = make_float4(aR[1][0],aR[1][1],aR[1][2],aR[1][3]);
        __syncthreads();
        if (tid < 128) {
          int b=tid>>6, c=tid&63;
          float sa=0.f, sr=0.f;
          #pragma unroll
          for (int e=0;e<32;++e){ sa+=P[0][e][b][c]; sr+=P[1][e][b][c]; }
          float va = fmaxf(sa + x_l[b][2]*wma0 + x_l[b][3]*wma1 + x_l[b][4]*wma2, 0.f);
          float vr = fmaxf(sr + x_l[b][0]*wsr0 + x_l[b][1]*wsr1, 0.f);
          if (t<=32) r_hist[t][b][c]=vr;
          st64s(&st64[(unsigned)((t&3)*32768) + (unsigned)((b0+b)*HH + cc2)], pack2(va,vr));
          aF[b][c0+c]=va; rF[b][c0+c]=vr;   // own slice of state(t)
        }
        __syncthreads();
      }
      if (t+1 < NSTEPS && tid < 10)
        x_l[tid/5][tid%5] = x_in[((t+1)*128 + b0 + tid/5)*5 + tid%5];
    }

    // ================= fin: finish o(t-1) (late mu poll) =================
    const int tp = t - 1;
    const bool fin = (t >= 1) && (tp <= 32 || tp >= 56);
    if (fin) {
      const int m = (tp <= 32) ? tp : tp - 23;
      {
        const int p = tid & 31, ch = tid >> 5;
        const u64* base = &mu64[(unsigned)(((m&3)*4 + jsl)*64)*32u];
        u64 vals[4]; unsigned rm = 0;
        const u64* ptrs[4];
        #pragma unroll
        for (int gg=0; gg<4; ++gg) ptrs[gg] = &base[(unsigned)((ch*4+gg)*32 + p)];
        while (rm != 0xFu) {
          #pragma unroll
          for (int gg=0; gg<4; ++gg) if (!(rm & (1u<<gg))) {
            u64 v = ld64(ptrs[gg]);
            if ((unsigned)v != SENT_MU && (unsigned)(v>>32) != SENT_MU) { vals[gg]=v; rm |= 1u<<gg; }
          }
        }
        float s0=0.f, s1=0.f;
        #pragma unroll
        for (int gg=0; gg<4; ++gg) { s0 += __uint_as_float((unsigned)vals[gg]);
                                     s1 += __uint_as_float((unsigned)(vals[gg]>>32)); }
        muG[ch][p][0]=s0; muG[ch][p][1]=s1;
      }
      __syncthreads();
      if (tid < 32) {   // reduce + re-sentinel slot (m+3)%4 (occupant m-1: consumed by all)
        float s0=0.f,s1=0.f;
        #pragma unroll
        for (int ch2=0;ch2<16;++ch2){ s0+=muG[ch2][tid][0]; s1+=muG[ch2][tid][1]; }
        mu_l[2*tid]=s0*(1.f/128.f); mu_l[2*tid+1]=s1*(1.f/128.f);
        st64s(&mu64[(unsigned)((((m+3)&3)*4 + jsl)*64 + grp)*32u + (unsigned)tid], SENT_MU_PAIR);
      }
      __syncthreads();
      if (tid < 128) {
        int b=tid>>6, c=tid&63;
        float o = fmaxf(gv*(opre[b][c]-mu_l[c]) + bv, 0.f);
        opre[b][c]=o;
        if (tp<=32) o_hist[tp][b][c0+c]=o;     // own cols of full-width hist
      }
      __syncthreads();
      if (tp <= 32 && tid < 64) {              // o broadcast (per-grp row): write-once slot
        st64s(&o64[(unsigned)((tp*64 + grp)*HH) + (unsigned)(c0 + tid)],
              pack2(opre[0][tid], opre[1][tid]));
      }
      if (tp >= 56 && tid < 320) {
        int ow=tid>>4, l16=tid&15, b=ow/10, n=ow%10;
        float acc=0.f;
        #pragma unroll
        for (int i2=0;i2<4;++i2){ int c=l16*4+i2; acc += opre[b][c]*W_y[(c0+c)*10+n]; }
        acc+=__shfl_xor(acc,1); acc+=__shfl_xor(acc,2);
        acc+=__shfl_xor(acc,4); acc+=__shfl_xor(acc,8);
        if (l16==0) atomicAdd(&out[(tp-56)*1280 + (b0+b)*10 + n], acc);
      }
    }
    if (t == NSTEPS) break;

    const bool live = (t <= 32 || t >= 56);
    const int mc = (t <= 32) ? t : t - 23;
    const int smax = (t-1 < 32) ? (t-1) : 32;

    // ======== gather: state(t) (tid>=128) ∥ o(t-1) peers (tid<96, tp<=32) ========
    if (tid >= 128) {
      const int w = tid - 128;                 // 384 threads: 3 peers x 128 words
      const int pi = w >> 7, w2 = w & 127, b = w2>>6, c64 = w2&63;
      const int jp = (jsl + 1 + pi) & 3;
      const u64* ptr = &st64[(unsigned)((t&3)*32768) + (unsigned)((b0+b)*HH + jp*64 + c64)];
      u64 v;
      for (;;){ v = ld64(ptr); if (v != SENT_STATE) break; }
      aF[b][jp*64+c64] = __uint_as_float((unsigned)v);
      rF[b][jp*64+c64] = __uint_as_float((unsigned)(v>>32));
    } else if (tid < 96 && t >= 1 && tp <= 32) {
      // 96 threads x 2 u64 = 192 peer cols of o(t-1), own grp row
      const u64* ptrs[2]; int cols[2]; u64 vals[2]; unsigned rm = 0;
      #pragma unroll
      for (int i=0;i<2;++i) {
        int idx = tid*2 + i;                   // 0..191
        int jp = (jsl + 1 + (idx>>6)) & 3, c64 = idx & 63;
        cols[i] = jp*64 + c64;
        ptrs[i] = &o64[(unsigned)((tp*64 + grp)*HH) + (unsigned)cols[i]];
      }
      while (rm != 3u) {
        #pragma unroll
        for (int i=0;i<2;++i) if (!(rm & (1u<<i))) {
          u64 v = ld64(ptrs[i]);
          if (v != SENT_STATE) { vals[i]=v; rm |= 1u<<i; }
        }
      }
      #pragma unroll
      for (int i=0;i<2;++i) {
        o_hist[tp][0][cols[i]] = __uint_as_float((unsigned)vals[i]);
        o_hist[tp][1][cols[i]] = __uint_as_float((unsigned)(vals[i]>>32));
      }
    }
    __syncthreads();
    // state re-sentinel slot (t+3)%4 (occupant t-1; peers' gather(t-1) proven done)
    if (tid < 128) {
      int b=tid>>6;
      st64s(&st64[(unsigned)(((t+3)&3)*32768) + (unsigned)((b0+b)*HH + cc2)], SENT_STATE);
    }

    // ================= dots (LOCAL, full width) + B: o_pre + apply + mu =================
    if (live) {
      // dots: c_s[b] = <rF[b,:], o_hist[s][b,:]> over 256 cols, 8 lanes/item
      const int l8 = tid & 7;
      for (int pp = tid>>3; pp < (smax+1)*2; pp += 64) {
        const int s = pp>>1, b2 = pp&1;
        float acc = 0.f;
        #pragma unroll
        for (int j=0;j<4;++j) {
          const int cb = j*64 + l8*8;
          #pragma unroll
          for (int i2=0;i2<4;++i2) {
            const float2 rv = *(const float2*)&rF[b2][cb + i2*2];
            const float2 ov = *(const float2*)&o_hist[s][b2][cb + i2*2];
            acc += rv.x*ov.x + rv.y*ov.y;
          }
        }
        acc+=__shfl_xor(acc,1); acc+=__shfl_xor(acc,2); acc+=__shfl_xor(acc,4);
        if (l8==0) c_l[s][b2]=acc;
      }
      // B matvec: o_pre partials (fp32 weights streamed from L2)
      const int kb = ks*8;
      float sa0[8],sa1[8],sr0[8],sr1[8];
      *(float4*)&sa0[0]=*(const float4*)&aF[0][kb]; *(float4*)&sa0[4]=*(const float4*)&aF[0][kb+4];
      *(float4*)&sa1[0]=*(const float4*)&aF[1][kb]; *(float4*)&sa1[4]=*(const float4*)&aF[1][kb+4];
      *(float4*)&sr0[0]=*(const float4*)&rF[0][kb]; *(float4*)&sr0[4]=*(const float4*)&rF[0][kb+4];
      *(float4*)&sr1[0]=*(const float4*)&rF[1][kb]; *(float4*)&sr1[4]=*(const float4*)&rF[1][kb+4];
      float aO[2][4]={{0.f,0.f,0.f,0.f},{0.f,0.f,0.f,0.f}};
      #pragma unroll
      for (int kk=0;kk<8;++kk){
        const int k=kb+kk;
        const float4 wo=*(const float4*)&W_ro[k*HH + c0 + q*4];
        const float4 wq=*(const float4*)&W_ao[k*HH + c0 + q*4];
        #pragma unroll
        for (int jj=0;jj<4;++jj){
          aO[0][jj] += sr0[kk]*(&wo.x)[jj] + sa0[kk]*(&wq.x)[jj];
          aO[1][jj] += sr1[kk]*(&wo.x)[jj] + sa1[kk]*(&wq.x)[jj];
        }
      }
      *(float4*)&P[0][ks][0][q*4] = make_float4(aO[0][0],aO[0][1],aO[0][2],aO[0][3]);
      *(float4*)&P[0][ks][1][q*4] = make_float4(aO[1][0],aO[1][1],aO[1][2],aO[1][3]);
      __syncthreads();
      if (tid < 128) {
        int b=tid>>6, c=tid&63;
        float s=0.f;
        #pragma unroll
        for (int e=0;e<32;++e) s+=P[0][e][b][c];
        for (int s2=0;s2<=smax;++s2)
          s += lam_pow[t-1-s2]*0.5f*c_l[s2][b]*r_hist[s2][b][c];
        opre[b][c]=s;
      }
      __syncthreads();
      if (tid < 32) {
        float plo=opre[0][2*tid]+opre[1][2*tid];
        float phi=opre[0][2*tid+1]+opre[1][2*tid+1];
        st64s(&mu64[(unsigned)(((mc&3)*4 + jsl)*64 + grp)*32u + (unsigned)tid], pack2(plo,phi));
      }
    }
  }
}

extern "C" void kernel_launch(void* const* d_in, const int* in_sizes, int n_in,
                              void* d_out, int out_size, void* d_ws, size_t ws_size,
                              hipStream_t stream) {
  if (ws_size < (size_t)WS_FLOATS * 4) return;   // ~5.6 MB scratch
  const float* x_in = (const float*)d_in[0];
  const float* W_sr = (const float*)d_in[1];
  const float* W_ma = (const float*)d_in[2];
  const float* W_ro = (const float*)d_in[3];
  const float* W_ao = (const float*)d_in[4];
  const float* W_ar = (const float*)d_in[5];
  const float* W_ra = (const float*)d_in[6];
  const float* W_a  = (const float*)d_in[7];
  const float* W_y  = (const float*)d_in[8];
  const float* g    = (const float*)d_in[9];
  const float* b    = (const float*)d_in[10];
  float* out = (float*)d_out;
  float* ws  = (float*)d_ws;

  hipLaunchKernelGGL(smn_init, dim3(256), dim3(256), 0, stream, ws, out);
  hipLaunchKernelGGL(smn_main, dim3(256), dim3(512), 0, stream,
                     x_in, W_sr, W_ma, W_ro, W_ao, W_ar, W_ra, W_a, W_y, g, b,
                     out, ws);
}

// Round 12
// 384.117 us; speedup vs baseline: 1.0461x; 1.0461x over previous
//
#include <hip/hip_runtime.h>

// SimpleMemoryNetwork: T=64,B=128,H=256,NI=2,NO=10, lambda=.95, eta=.5, sample=32, decision=8
// R12 = R6 (best 367us: 256 blocks = 64 batch-groups x 4 col-slices, 512 thr, 1 blk/CU,
// barrier-free sentinel dataflow, late mu poll) + SAME-XCD L2-LOCAL FAST PATH:
//  * startup: each block reads HW_REG_XCC_ID, publishes it; each group of 4 peers checks
//    "all on one XCD". If yes -> state/c exchanges use sc0-only (stop at shared L2,
//    ~200cy RT). If no -> sc0 sc1 bypass (L3 coherence point) = exact R6 behavior.
//  * mu (cross-group all-reduce) always sc0 sc1. Sentinel/slot protocol unchanged;
//    ordering proofs are cache-level-agnostic (producer+consumer same level per region).
// Safe by construction: fallback == R6.

typedef unsigned long long u64;

#define HH 256
#define NSTEPS 64

// ws layout (float offsets)
#define OFF_ST  0u          // st64[4][128][256] u64
#define OFF_C   262144u     // c_parts[4][33][128][4] f32
#define OFF_MU  329728u     // mu64[4][4][64][32] u64
#define OFF_XCC 395264u     // xcc[256] int
#define WS_FLOATS 395520u   // ~1.58 MB

#define SENT_STATE   0xBF800000BF800000ull
#define SENT_C       0xBF800000u
#define SENT_MU      0x7FC00000u
#define SENT_MU_PAIR 0x7FC000007FC00000ull

#define AGENT __HIP_MEMORY_SCOPE_AGENT
#define RLX   __ATOMIC_RELAXED

__device__ __forceinline__ u64 ld64(const u64* p){ return __hip_atomic_load(p,RLX,AGENT); }
__device__ __forceinline__ void st64s(u64* p,u64 v){ __hip_atomic_store(p,v,RLX,AGENT); }
__device__ __forceinline__ float ld32f(const float* p){ return __hip_atomic_load(p,RLX,AGENT); }
__device__ __forceinline__ void st32f(float* p,float v){ __hip_atomic_store(p,v,RLX,AGENT); }
// same-XCD fast path: sc0 only -> visible at the XCD's shared L2 (vL1 write-through)
__device__ __forceinline__ u64 ld64_l2(const u64* p){
  u64 v; asm volatile("global_load_dwordx2 %0, %1, off sc0\ns_waitcnt vmcnt(0)"
                      :"=v"(v):"v"(p):"memory"); return v;
}
__device__ __forceinline__ void st64_l2(u64* p,u64 v){
  asm volatile("global_store_dwordx2 %0, %1, off sc0"::"v"(p),"v"(v):"memory");
}
__device__ __forceinline__ float ld32_l2(const float* p){
  float v; asm volatile("global_load_dword %0, %1, off sc0\ns_waitcnt vmcnt(0)"
                        :"=v"(v):"v"(p):"memory"); return v;
}
__device__ __forceinline__ void st32_l2(float* p,float v){
  asm volatile("global_store_dword %0, %1, off sc0"::"v"(p),"v"(v):"memory");
}
__device__ __forceinline__ u64 pack2(float lo,float hi){
  return (u64)__float_as_uint(lo) | ((u64)__float_as_uint(hi)<<32);
}

__global__ __launch_bounds__(256) void smn_init(float* __restrict__ ws,
                                                float* __restrict__ out){
  unsigned i = blockIdx.x*256u + threadIdx.x, st = gridDim.x*256u;
  u64* stp=(u64*)(ws+OFF_ST); float* cp=ws+OFF_C; u64* mp=(u64*)(ws+OFF_MU);
  int* xp=(int*)(ws+OFF_XCC);
  for (unsigned k=i;k<131072u;k+=st) st64s(&stp[k],SENT_STATE);
  for (unsigned k=i;k<67584u;k+=st)  st32f(&cp[k],__uint_as_float(SENT_C));
  for (unsigned k=i;k<32768u;k+=st)  st64s(&mp[k],SENT_MU_PAIR);
  for (unsigned k=i;k<256u;k+=st)    __hip_atomic_store(&xp[k], -1, RLX, AGENT);
  for (unsigned k=i;k<10240u;k+=st)  out[k]=0.f;
}

__global__ __launch_bounds__(512) void smn_main(
    const float* __restrict__ x_in, const float* __restrict__ W_sr,
    const float* __restrict__ W_ma, const float* __restrict__ W_ro,
    const float* __restrict__ W_ao, const float* __restrict__ W_ar,
    const float* __restrict__ W_ra, const float* __restrict__ W_a,
    const float* __restrict__ W_y,  const float* __restrict__ gvec,
    const float* __restrict__ bvec, float* __restrict__ out,
    float* __restrict__ ws)
{
  __shared__ __align__(16) float aF[2][HH], rF[2][HH];   // full state(t)
  __shared__ __align__(16) float P[2][32][2][64];        // k-split matvec partials
  __shared__ __align__(16) float r_hist[33][2][64];
  __shared__ __align__(16) float o_hist[33][2][64];
  __shared__ float opre[2][64];
  __shared__ float c_l[33][2];
  __shared__ float mu_l[64];
  __shared__ float muG[16][32][2];
  __shared__ float lam_pow[64];
  __shared__ float x_l[2][5];
  __shared__ int   fastF;
  __shared__ float lds_pad[8192];     // LDS > 80KB => 1 block/CU

  const int tid = threadIdx.x;
  const int bid = blockIdx.x;
  const int grp = bid >> 2, jsl = bid & 3;
  const int b0 = grp * 2, c0 = jsl * 64;
  const int q = tid & 15, ks = tid >> 4;       // matvec map: col quad, k-slice of 8

  u64*   st64    = (u64*)(ws + OFF_ST);
  float* c_parts = ws + OFF_C;
  u64*   mu64    = (u64*)(ws + OFF_MU);
  int*   xcc_arr = (int*)(ws + OFF_XCC);

  if (out == nullptr) lds_pad[tid] = 1.f;      // never true; keeps pad allocated

  // ---- startup: same-XCD detection (safe fallback = R6 slow path) ----
  {
    unsigned myxcc;
    asm volatile("s_getreg_b32 %0, hwreg(HW_REG_XCC_ID)" : "=s"(myxcc));
    if (tid == 0) {
      __hip_atomic_store(&xcc_arr[bid], (int)myxcc, RLX, AGENT);
      int e[4];
      #pragma unroll
      for (int i=0;i<4;++i) {
        do { e[i] = __hip_atomic_load(&xcc_arr[grp*4+i], RLX, AGENT); } while (e[i] < 0);
      }
      fastF = (e[0]==e[1] && e[1]==e[2] && e[2]==e[3]) ? 1 : 0;
    }
  }

  // per-thread column constants (combine map tid<128 -> b=tid>>6, c=tid&63)
  const int cc2 = c0 + (tid & 63);
  const float gv  = gvec[cc2], bv = bvec[cc2];
  const float wma0=W_ma[cc2], wma1=W_ma[HH+cc2], wma2=W_ma[2*HH+cc2];
  const float wsr0=W_sr[cc2], wsr1=W_sr[HH+cc2];
  if (tid < 64) lam_pow[tid] = powf(0.95f,(float)tid);
  if (tid < 10) x_l[tid/5][tid%5] = x_in[(b0 + tid/5)*5 + tid%5];   // x(0)
  __syncthreads();
  const bool fast = (fastF != 0);

  for (int t = 0; t <= NSTEPS; ++t) {
    // ================= A: state(t) own slice =================
    if (t < NSTEPS) {
      if (t == 0) {
        if (tid < 128) {
          int b = tid>>6, c = tid&63;
          float va = fmaxf(x_l[b][2]*wma0 + x_l[b][3]*wma1 + x_l[b][4]*wma2, 0.f);
          float vr = fmaxf(x_l[b][0]*wsr0 + x_l[b][1]*wsr1, 0.f);
          aF[b][c0+c]=va; rF[b][c0+c]=vr; r_hist[0][b][c]=vr;
          u64* p = &st64[(unsigned)((b0+b)*HH + cc2)];
          if (fast) st64_l2(p, pack2(va,vr)); else st64s(p, pack2(va,vr));
        }
        __syncthreads();
      } else {
        const int kb = ks*8;
        float sa0[8],sa1[8],sr0[8],sr1[8];
        *(float4*)&sa0[0]=*(const float4*)&aF[0][kb]; *(float4*)&sa0[4]=*(const float4*)&aF[0][kb+4];
        *(float4*)&sa1[0]=*(const float4*)&aF[1][kb]; *(float4*)&sa1[4]=*(const float4*)&aF[1][kb+4];
        *(float4*)&sr0[0]=*(const float4*)&rF[0][kb]; *(float4*)&sr0[4]=*(const float4*)&rF[0][kb+4];
        *(float4*)&sr1[0]=*(const float4*)&rF[1][kb]; *(float4*)&sr1[4]=*(const float4*)&rF[1][kb+4];
        float aA[2][4]={{0.f,0.f,0.f,0.f},{0.f,0.f,0.f,0.f}};
        float aR[2][4]={{0.f,0.f,0.f,0.f},{0.f,0.f,0.f,0.f}};
        #pragma unroll
        for (int kk=0; kk<8; ++kk) {
          const int k = kb + kk;
          const float4 wa = *(const float4*)&W_a [k*HH + c0 + q*4];
          const float4 wr = *(const float4*)&W_ra[k*HH + c0 + q*4];
          const float4 wn = *(const float4*)&W_ar[k*HH + c0 + q*4];
          #pragma unroll
          for (int jj=0;jj<4;++jj){
            const float waj=(&wa.x)[jj], wrj=(&wr.x)[jj], wnj=(&wn.x)[jj];
            aA[0][jj] += sa0[kk]*waj + sr0[kk]*wrj;
            aA[1][jj] += sa1[kk]*waj + sr1[kk]*wrj;
            aR[0][jj] += sa0[kk]*wnj;
            aR[1][jj] += sa1[kk]*wnj;
          }
        }
        *(float4*)&P[0][ks][0][q*4] = make_float4(aA[0][0],aA[0][1],aA[0][2],aA[0][3]);
        *(float4*)&P[0][ks][1][q*4] = make_float4(aA[1][0],aA[1][1],aA[1][2],aA[1][3]);
        *(float4*)&P[1][ks][0][q*4] = make_float4(aR[0][0],aR[0][1],aR[0][2],aR[0][3]);
        *(float4*)&P[1][ks][1][q*4] = make_float4(aR[1][0],aR[1][1],aR[1][2],aR[1][3]);
        __syncthreads();
        if (tid < 128) {
          int b=tid>>6, c=tid&63;
          float sa=0.f, sr=0.f;
          #pragma unroll
          for (int e=0;e<32;++e){ sa+=P[0][e][b][c]; sr+=P[1][e][b][c]; }
          float va = fmaxf(sa + x_l[b][2]*wma0 + x_l[b][3]*wma1 + x_l[b][4]*wma2, 0.f);
          float vr = fmaxf(sr + x_l[b][0]*wsr0 + x_l[b][1]*wsr1, 0.f);
          if (t<=32) r_hist[t][b][c]=vr;
          u64* p = &st64[(unsigned)((t&3)*32768) + (unsigned)((b0+b)*HH + cc2)];
          if (fast) st64_l2(p, pack2(va,vr)); else st64s(p, pack2(va,vr));
          aF[b][c0+c]=va; rF[b][c0+c]=vr;   // own slice of state(t)
        }
        __syncthreads();
      }
      if (t+1 < NSTEPS && tid < 10)
        x_l[tid/5][tid%5] = x_in[((t+1)*128 + b0 + tid/5)*5 + tid%5];
    }

    // ================= fin: finish o(t-1) (late mu poll, always sc0sc1) =========
    const int tp = t - 1;
    const bool fin = (t >= 1) && (tp <= 32 || tp >= 56);
    if (fin) {
      const int m = (tp <= 32) ? tp : tp - 23;
      {
        const int p = tid & 31, ch = tid >> 5;
        const u64* base = &mu64[(unsigned)(((m&3)*4 + jsl)*64)*32u];
        u64 vals[4]; unsigned rm = 0;
        const u64* ptrs[4];
        #pragma unroll
        for (int gg=0; gg<4; ++gg) ptrs[gg] = &base[(unsigned)((ch*4+gg)*32 + p)];
        while (rm != 0xFu) {
          #pragma unroll
          for (int gg=0; gg<4; ++gg) if (!(rm & (1u<<gg))) {
            u64 v = ld64(ptrs[gg]);
            if ((unsigned)v != SENT_MU && (unsigned)(v>>32) != SENT_MU) { vals[gg]=v; rm |= 1u<<gg; }
          }
        }
        float s0=0.f, s1=0.f;
        #pragma unroll
        for (int gg=0; gg<4; ++gg) { s0 += __uint_as_float((unsigned)vals[gg]);
                                     s1 += __uint_as_float((unsigned)(vals[gg]>>32)); }
        muG[ch][p][0]=s0; muG[ch][p][1]=s1;
      }
      __syncthreads();
      if (tid < 32) {   // reduce + re-sentinel slot (m+3)%4 (occupant m-1: consumed by all)
        float s0=0.f,s1=0.f;
        #pragma unroll
        for (int ch2=0;ch2<16;++ch2){ s0+=muG[ch2][tid][0]; s1+=muG[ch2][tid][1]; }
        mu_l[2*tid]=s0*(1.f/128.f); mu_l[2*tid+1]=s1*(1.f/128.f);
        st64s(&mu64[(unsigned)((((m+3)&3)*4 + jsl)*64 + grp)*32u + (unsigned)tid], SENT_MU_PAIR);
      }
      __syncthreads();
      if (tid < 128) {
        int b=tid>>6, c=tid&63;
        float o = fmaxf(gv*(opre[b][c]-mu_l[c]) + bv, 0.f);
        opre[b][c]=o;
        if (tp<=32) o_hist[tp][b][c]=o;
      }
      __syncthreads();
      if (tp >= 56 && tid < 320) {
        int ow=tid>>4, l16=tid&15, b=ow/10, n=ow%10;
        float acc=0.f;
        #pragma unroll
        for (int i2=0;i2<4;++i2){ int c=l16*4+i2; acc += opre[b][c]*W_y[(c0+c)*10+n]; }
        acc+=__shfl_xor(acc,1); acc+=__shfl_xor(acc,2);
        acc+=__shfl_xor(acc,4); acc+=__shfl_xor(acc,8);
        if (l16==0) atomicAdd(&out[(tp-56)*1280 + (b0+b)*10 + n], acc);
      }
    }
    if (t == NSTEPS) break;

    const bool live = (t <= 32 || t >= 56);
    const int mc = (t <= 32) ? t : t - 23;
    const int smax = (t-1 < 32) ? (t-1) : 32;

    // ======== dots publish (tid<128, live) || state(t) gather (tid>=128) ========
    if (tid < 128) {
      if (live && smax >= 0) {
        const int l8 = tid & 7;
        for (int pp = tid>>3; pp < (smax+1)*2; pp += 16) {
          const int s = pp>>1, b2 = pp&1;
          float acc=0.f;
          #pragma unroll
          for (int i2=0;i2<8;++i2){ int c=l8*8+i2; acc += rF[b2][c0+c]*o_hist[s][b2][c]; }
          acc+=__shfl_xor(acc,1); acc+=__shfl_xor(acc,2); acc+=__shfl_xor(acc,4);
          if (l8==0) {
            float* p = &c_parts[(unsigned)((((mc&3)*33+s)*128 + b0+b2)*4 + jsl)];
            if (fast) st32_l2(p, acc); else st32f(p, acc);
          }
        }
      }
    } else {
      const int w = tid - 128;                 // 384 threads: 3 peers x 128 words
      const int pi = w >> 7, w2 = w & 127, b = w2>>6, c64 = w2&63;
      const int jp = (jsl + 1 + pi) & 3;
      const u64* ptr = &st64[(unsigned)((t&3)*32768) + (unsigned)((b0+b)*HH + jp*64 + c64)];
      u64 v;
      if (fast) { for (;;){ v = ld64_l2(ptr); if (v != SENT_STATE) break; } }
      else      { for (;;){ v = ld64(ptr);    if (v != SENT_STATE) break; } }
      aF[b][jp*64+c64] = __uint_as_float((unsigned)v);
      rF[b][jp*64+c64] = __uint_as_float((unsigned)(v>>32));
    }
    __syncthreads();
    // state re-sentinel slot (t+3)%4 (occupant t-1; peers' gather(t-1) proven done)
    if (tid < 128) {
      int b=tid>>6;
      u64* p = &st64[(unsigned)(((t+3)&3)*32768) + (unsigned)((b0+b)*HH + cc2)];
      if (fast) st64_l2(p, SENT_STATE); else st64s(p, SENT_STATE);
    }

    // ================= B: o_pre + apply + mu publish (live only) =================
    if (live) {
      const int kb = ks*8;
      float sa0[8],sa1[8],sr0[8],sr1[8];
      *(float4*)&sa0[0]=*(const float4*)&aF[0][kb]; *(float4*)&sa0[4]=*(const float4*)&aF[0][kb+4];
      *(float4*)&sa1[0]=*(const float4*)&aF[1][kb]; *(float4*)&sa1[4]=*(const float4*)&aF[1][kb+4];
      *(float4*)&sr0[0]=*(const float4*)&rF[0][kb]; *(float4*)&sr0[4]=*(const float4*)&rF[0][kb+4];
      *(float4*)&sr1[0]=*(const float4*)&rF[1][kb]; *(float4*)&sr1[4]=*(const float4*)&rF[1][kb+4];
      float aO[2][4]={{0.f,0.f,0.f,0.f},{0.f,0.f,0.f,0.f}};
      #pragma unroll
      for (int kk=0;kk<8;++kk){
        const int k=kb+kk;
        const float4 wo=*(const float4*)&W_ro[k*HH + c0 + q*4];
        const float4 wq=*(const float4*)&W_ao[k*HH + c0 + q*4];
        #pragma unroll
        for (int jj=0;jj<4;++jj){
          aO[0][jj] += sr0[kk]*(&wo.x)[jj] + sa0[kk]*(&wq.x)[jj];
          aO[1][jj] += sr1[kk]*(&wo.x)[jj] + sa1[kk]*(&wq.x)[jj];
        }
      }
      *(float4*)&P[0][ks][0][q*4] = make_float4(aO[0][0],aO[0][1],aO[0][2],aO[0][3]);
      *(float4*)&P[0][ks][1][q*4] = make_float4(aO[1][0],aO[1][1],aO[1][2],aO[1][3]);
      // c gather: 4 parts per (s,b), shfl-sum
      if (smax >= 0 && tid < (smax+1)*8) {
        const int s=tid>>3, b2=(tid>>2)&1, jj2=tid&3;
        const float* ptr=&c_parts[(unsigned)((((mc&3)*33+s)*128 + b0+b2)*4 + jj2)];
        float v;
        if (fast) { for(;;){ v=ld32_l2(ptr); if (__float_as_uint(v)!=SENT_C) break; } }
        else      { for(;;){ v=ld32f(ptr);   if (__float_as_uint(v)!=SENT_C) break; } }
        v+=__shfl_xor(v,1); v+=__shfl_xor(v,2);
        if (jj2==0) c_l[s][b2]=v;
      }
      __syncthreads();
      // c re-sentinel slot (mc+3)%4 (occupant mc-1: consumed by all group peers)
      if (smax >= 0 && tid >= 128 && tid < 194) {
        const int s=(tid-128)>>1, b2=(tid-128)&1;
        float* p = &c_parts[(unsigned)(((((mc+3)&3)*33+s)*128 + b0+b2)*4 + jsl)];
        if (fast) st32_l2(p, __uint_as_float(SENT_C)); else st32f(p, __uint_as_float(SENT_C));
      }
      if (tid < 128) {
        int b=tid>>6, c=tid&63;
        float s=0.f;
        #pragma unroll
        for (int e=0;e<32;++e) s+=P[0][e][b][c];
        for (int s2=0;s2<=smax;++s2)
          s += lam_pow[t-1-s2]*0.5f*c_l[s2][b]*r_hist[s2][b][c];
        opre[b][c]=s;
      }
      __syncthreads();
      if (tid < 32) {
        float plo=opre[0][2*tid]+opre[1][2*tid];
        float phi=opre[0][2*tid+1]+opre[1][2*tid+1];
        st64s(&mu64[(unsigned)(((mc&3)*4 + jsl)*64 + grp)*32u + (unsigned)tid], pack2(plo,phi));
      }
    }
  }
}

extern "C" void kernel_launch(void* const* d_in, const int* in_sizes, int n_in,
                              void* d_out, int out_size, void* d_ws, size_t ws_size,
                              hipStream_t stream) {
  if (ws_size < (size_t)WS_FLOATS * 4) return;   // ~1.6 MB scratch
  const float* x_in = (const float*)d_in[0];
  const float* W_sr = (const float*)d_in[1];
  const float* W_ma = (const float*)d_in[2];
  const float* W_ro = (const float*)d_in[3];
  const float* W_ao = (const float*)d_in[4];
  const float* W_ar = (const float*)d_in[5];
  const float* W_ra = (const float*)d_in[6];
  const float* W_a  = (const float*)d_in[7];
  const float* W_y  = (const float*)d_in[8];
  const float* g    = (const float*)d_in[9];
  const float* b    = (const float*)d_in[10];
  float* out = (float*)d_out;
  float* ws  = (float*)d_ws;

  hipLaunchKernelGGL(smn_init, dim3(256), dim3(256), 0, stream, ws, out);
  hipLaunchKernelGGL(smn_main, dim3(256), dim3(512), 0, stream,
                     x_in, W_sr, W_ma, W_ro, W_ao, W_ar, W_ra, W_a, W_y, g, b,
                     out, ws);
}